// Round 11
// baseline (15.257 us; speedup 1.0000x reference)
//
#include <hip/hip_runtime.h>
#include <math.h>

#define EPSF 1e-7f

__constant__ float c_anch[3][3][2] = {
    {{80.f,104.f},{128.f,240.f},{264.f,184.f}},
    {{480.f,976.f},{992.f,720.f},{944.f,1904.f}},
    {{3712.f,2880.f},{4992.f,6336.f},{11936.f,10432.f}}
};
__constant__ float c_stride[3] = {8.f, 16.f, 32.f};
__constant__ float c_bal[3]    = {4.f, 1.f, 0.4f};
__constant__ int   c_HW[3]     = {6400, 1600, 400};
__constant__ int   c_W[3]      = {80, 40, 20};

// Module-scope (zero-init, immune to ws poison), strictly monotone:
// every call adds exactly 1 to each tag and 1 to the epoch, so during call k
// the poller (block 399) waits for all tags >= k. Deterministic on the
// correctness call, every timed replay, and every rocprof replay pass.
__device__ unsigned int g_tag[400];
__device__ unsigned int g_epoch;

__device__ __forceinline__ float bce0(float x) {
    // BCE with target 0: max(x,0) + log(1+exp(-|x|))
    return fmaxf(x, 0.f) + __logf(1.f + __expf(-fabsf(x)));
}

__device__ __forceinline__ void agent_store(float* p, float v) {
    __hip_atomic_store(p, v, __ATOMIC_RELAXED, __HIP_MEMORY_SCOPE_AGENT);
}
__device__ __forceinline__ float agent_load(const float* p) {
    return __hip_atomic_load(p, __ATOMIC_RELAXED, __HIP_MEMORY_SCOPE_AGENT);
}

// ---------------------------------------------------------------------------
// Single kernel (400 blocks x 256):
//   all blocks      : 252-float4 slice of the dense objectness reduce
//   blocks [0,384)  : positive targets, register-resident build (no barrier)
//   each block      : partial {box, obj, cls} via sc1 stores, then a RELEASE
//                     fetch_add on its PRIVATE tag (no contention, no inval)
//   block 399       : polls the 400 tags, 1 acquire fence, finalize -> out[0]
// ---------------------------------------------------------------------------
__global__ __launch_bounds__(256) void fused_all(
        const float* __restrict__ p0, const float* __restrict__ p1,
        const float* __restrict__ p2,
        const float* __restrict__ boxes, const int* __restrict__ labels,
        float* __restrict__ part, float* __restrict__ nposPart,
        float* __restrict__ out)
{
    __shared__ float red[4][8];
    __shared__ unsigned int sEpoch;

    const int bid  = blockIdx.x;
    const int tid  = threadIdx.x;
    const int lane = tid & 63, wv = tid >> 6;

    const bool isPos = (bid < 384);
    const int s   = bid >> 7;            // valid for pos blocks
    const int b   = (bid >> 3) & 15;
    const int grp = bid & 7;             // target n = grp*4 + wave

    // ---- issue boxes/labels loads first (pos blocks, lanes < 32) ----
    float4 bx; int labl = 0;
    if (isPos && lane < 32) {
        bx   = ((const float4*)boxes)[b * 32 + lane];
        labl = labels[b * 32 + lane];
    }

    // ---------------- dense objectness slice (all blocks) ----------------
    float dsum = 0.f;
    {
        int v = bid * 252 + tid;                 // 400*252 = 100800 exactly
        if (tid < 252) {
            int sc, run, off, HW;
            const float* pred;
            if (v < 76800)      { sc = 0; HW = 6400; run = v / 1600;          off = v - run * 1600;         pred = p0; }
            else if (v < 96000) { sc = 1; HW = 1600; int u = v - 76800; run = u / 400; off = u - run * 400; pred = p1; }
            else                { sc = 2; HW = 400;  int u = v - 96000; run = u / 100; off = u - run * 100; pred = p2; }
            int bb = run / 3, a = run - bb * 3;
            const float4* ptr = (const float4*)(pred + (size_t)(bb * 255 + a * 85 + 4) * HW) + off;
            float4 x = *ptr;
            float w = 0.5f * c_bal[sc];
            dsum = w * (bce0(x.x) + bce0(x.y) + bce0(x.z) + bce0(x.w));
        }
    }

    float boxc = 0.f, objc = 0.f, clsp = 0.f;
    if (isPos) {
        // ---- register target build (lanes < 32 hold target `lane`) ----
        int key = 0; float txl = 0.f, tyl = 0.f, twl = 0.f, thl = 0.f;
        {
            float cx = (bx.x + bx.z) * 0.5f, cy = (bx.y + bx.w) * 0.5f;
            float w  = bx.z - bx.x,          h  = bx.w - bx.y;
            float stride = c_stride[s];
            float xg = cx / stride, yg = cy / stride;
            int W = c_W[s];
            int gi = min(max((int)yg, 0), W - 1);   // row from y
            int gj = min(max((int)xg, 0), W - 1);   // col from x
            int best = 0; float bm = 1e30f;
            for (int k = 0; k < 3; ++k) {
                float aw = c_anch[s][k][0], ah = c_anch[s][k][1];
                float r0 = w / aw, r1 = h / ah;
                float m = fmaxf(r0, 1.f / r0) * fmaxf(r1, 1.f / r1);
                if (m < bm) { bm = m; best = k; }
            }
            float aw = c_anch[s][best][0], ah = c_anch[s][best][1];
            key = (best << 20) | (gi << 10) | gj;
            txl = xg - (float)gj;
            tyl = yg - (float)gi;
            twl = __logf(w / (aw + 1e-16f));
            thl = __logf(h / (ah + 1e-16f));
        }

        // npos: designated wave (block grp==0, wave 0) via shfl-rotate dup test
        if (grp == 0 && wv == 0) {
            bool dup = false;
            for (int d = 1; d < 32; ++d) {
                int nk = __shfl(key, (lane + d) & 31);
                dup |= ((lane + d) < 32) && (nk == key);
            }
            bool winl = (lane < 32) && !dup;
            unsigned long long bal = __ballot(winl);
            if (lane == 0) agent_store(&nposPart[s * 16 + b], (float)__popcll(bal));
        }

        // this wave's target n: broadcast from lane n, dedup via one ballot
        const int n = grp * 4 + wv;
        int   key_n = __shfl(key, n);
        float tx_n  = __shfl(txl, n);
        float ty_n  = __shfl(tyl, n);
        float tw_n  = __shfl(twl, n);
        float th_n  = __shfl(thl, n);
        int   lab   = __shfl(labl, n);
        unsigned long long dupm =
            __ballot((lane > n) && (lane < 32) && (key == key_n));
        bool win = (dupm == 0ull);        // last-n-wins scatter semantics

        if (win) {
            int a  = key_n >> 20;
            int gi = (key_n >> 10) & 1023;
            int gj = key_n & 1023;
            const int HW = c_HW[s], W = c_W[s];
            int hw = gi * W + gj;
            const float* pred = (s == 0) ? p0 : ((s == 1) ? p1 : p2);
            const float* pb_ = pred + (size_t)(b * 255 + a * 85) * HW + hw;
            const float* pc  = pb_ + (size_t)5 * HW;

            // lane-parallel class logit loads
            float xc0 = pc[(size_t)lane * HW];
            float xc1 = (lane < 16) ? pc[(size_t)(lane + 64) * HW] : 0.f;
            clsp = bce0(xc0) - ((lane == lab) ? xc0 : 0.f);
            if (lane < 16) clsp += bce0(xc1) - ((lane + 64 == lab) ? xc1 : 0.f);

            float px = pb_[0], py = pb_[(size_t)HW];
            float pw = pb_[2 * (size_t)HW], ph = pb_[3 * (size_t)HW];
            float xo = pb_[4 * (size_t)HW];

            // objectness correction:  bal * (0.5*bce0(xo) - xo)
            objc = c_bal[s] * (0.5f * bce0(xo) - xo);

            // CIoU (lane-redundant)
            const float stride = c_stride[s];
            const float aw = c_anch[s][a][0], ah = c_anch[s][a][1];
            float sx = 1.f / (1.f + __expf(-px));
            float sy = 1.f / (1.f + __expf(-py));
            float b1x = (sx + (float)gj) * stride, b1y = (sy + (float)gi) * stride;
            float b1w = __expf(pw) * aw,           b1h = __expf(ph) * ah;
            float b2x = ((float)gj + tx_n) * stride, b2y = ((float)gi + ty_n) * stride;
            float b2w = __expf(tw_n) * aw,           b2h = __expf(th_n) * ah;

            float b1x1 = b1x - b1w * 0.5f, b1x2 = b1x + b1w * 0.5f;
            float b1y1 = b1y - b1h * 0.5f, b1y2 = b1y + b1h * 0.5f;
            float b2x1 = b2x - b2w * 0.5f, b2x2 = b2x + b2w * 0.5f;
            float b2y1 = b2y - b2h * 0.5f, b2y2 = b2y + b2h * 0.5f;
            float iw = fmaxf(fminf(b1x2, b2x2) - fmaxf(b1x1, b2x1), 0.f);
            float ih = fmaxf(fminf(b1y2, b2y2) - fmaxf(b1y1, b2y1), 0.f);
            float inter = iw * ih;
            float uni = b1w * b1h + b2w * b2h - inter + EPSF;
            float iou = inter / uni;
            float cwv = fmaxf(b1x2, b2x2) - fminf(b1x1, b2x1);
            float chv = fmaxf(b1y2, b2y2) - fminf(b1y1, b2y1);
            float c2 = cwv * cwv + chv * chv + EPSF;
            float dx = b2x1 + b2x2 - b1x1 - b1x2;
            float dy = b2y1 + b2y2 - b1y1 - b1y2;
            float rho2 = (dx * dx + dy * dy) * 0.25f;
            float dat = atanf(b2w / (b2h + EPSF)) - atanf(b1w / (b1h + EPSF));
            float v = (4.f / (float)(M_PI * M_PI)) * dat * dat;
            float alpha = v / (v - iou + 1.f + EPSF);
            boxc = 1.f - (iou - (rho2 / c2 + v * alpha));
        }
    }

    // block reduce: {dsum, box, objc, cls} -> one float4-slot partial
    for (int o = 32; o > 0; o >>= 1) {
        dsum += __shfl_down(dsum, o);
        clsp += __shfl_down(clsp, o);
    }
    if (lane == 0) {
        red[wv][0] = dsum; red[wv][1] = boxc; red[wv][2] = objc; red[wv][3] = clsp;
    }
    __syncthreads();
    if (tid == 0) {
        float d = 0.f, bxs = 0.f, oc = 0.f, cl = 0.f;
        for (int i = 0; i < 4; ++i) {
            d += red[i][0]; bxs += red[i][1]; oc += red[i][2]; cl += red[i][3];
        }
        float* dst = part + (size_t)bid * 4;
        agent_store(dst + 0, bxs);
        agent_store(dst + 1, d + oc);     // obj = dense + corr
        agent_store(dst + 2, cl);
        // RELEASE on a private tag: drains this block's sc1 stores, no inval,
        // no cross-block address contention.
        __hip_atomic_fetch_add(&g_tag[bid], 1u,
                               __ATOMIC_RELEASE, __HIP_MEMORY_SCOPE_AGENT);
    }

    if (bid != 399) return;

    // ---------------- poller + finalize (block 399 only) ----------------
    if (tid == 0)
        sEpoch = __hip_atomic_fetch_add(&g_epoch, 1u,
                     __ATOMIC_RELAXED, __HIP_MEMORY_SCOPE_AGENT) + 1u;
    __syncthreads();
    const unsigned int epoch = sEpoch;
    for (int i = tid; i < 400; i += 256) {
        while ((int)(__hip_atomic_load(&g_tag[i], __ATOMIC_RELAXED,
                                       __HIP_MEMORY_SCOPE_AGENT) - epoch) < 0)
            __builtin_amdgcn_s_sleep(1);
    }
    __syncthreads();
    __builtin_amdgcn_fence(__ATOMIC_ACQUIRE, "agent");   // one acquire total

    float bx0 = 0.f, bx1 = 0.f, bx2 = 0.f, obj = 0.f, cls = 0.f;
    for (int i = tid; i < 400; i += 256) {
        const float* src = part + (size_t)i * 4;
        float bv = agent_load(src + 0);
        obj += agent_load(src + 1);
        cls += agent_load(src + 2);
        int sc = i >> 7;          // 128 blocks per scale; i>=384 -> sc=3 (box=0)
        bx0 += (sc == 0) ? bv : 0.f;
        bx1 += (sc == 1) ? bv : 0.f;
        bx2 += (sc == 2) ? bv : 0.f;
    }
    float np0 = 0.f, np1 = 0.f, np2 = 0.f;
    if (tid < 48) {
        float v = agent_load(&nposPart[tid]);
        int sc = tid / 16;
        np0 = (sc == 0) ? v : 0.f;
        np1 = (sc == 1) ? v : 0.f;
        np2 = (sc == 2) ? v : 0.f;
    }

    for (int o = 32; o > 0; o >>= 1) {
        bx0 += __shfl_down(bx0, o);
        bx1 += __shfl_down(bx1, o);
        bx2 += __shfl_down(bx2, o);
        obj += __shfl_down(obj, o);
        cls += __shfl_down(cls, o);
        np0 += __shfl_down(np0, o);
        np1 += __shfl_down(np1, o);
        np2 += __shfl_down(np2, o);
    }
    __syncthreads();              // red[] reuse
    if (lane == 0) {
        red[wv][0] = bx0; red[wv][1] = bx1; red[wv][2] = bx2; red[wv][3] = obj;
        red[wv][4] = cls; red[wv][5] = np0; red[wv][6] = np1; red[wv][7] = np2;
    }
    __syncthreads();
    if (tid == 0) {
        float v[8];
        for (int j = 0; j < 8; ++j)
            v[j] = red[0][j] + red[1][j] + red[2][j] + red[3][j];
        float tot = v[0] / fmaxf(v[5], 1.f)
                  + v[1] / fmaxf(v[6], 1.f)
                  + v[2] / fmaxf(v[7], 1.f)
                  + v[3]               // obj (dense + corrections, bal folded)
                  + 0.5f * v[4];       // LAMBDA_CLS
        out[0] = tot / 16.f;           // / B
    }
}

extern "C" void kernel_launch(void* const* d_in, const int* in_sizes, int n_in,
                              void* d_out, int out_size, void* d_ws, size_t ws_size,
                              hipStream_t stream)
{
    const float* p0     = (const float*)d_in[0];
    const float* p1     = (const float*)d_in[1];
    const float* p2     = (const float*)d_in[2];
    const float* boxes  = (const float*)d_in[3];
    const int*   labels = (const int*)d_in[4];

    char* ws = (char*)d_ws;
    float* part     = (float*)ws;               // 400*4 floats = 6400 B
    float* nposPart = (float*)(ws + 6656);      // 48*4 = 192 B

    fused_all<<<400, 256, 0, stream>>>(p0, p1, p2, boxes, labels,
                                       part, nposPart, (float*)d_out);
}

// Round 12
// 12.088 us; speedup vs baseline: 1.2622x; 1.2622x over previous
//
#include <hip/hip_runtime.h>
#include <math.h>

#define EPSF 1e-7f

__constant__ float c_anch[3][3][2] = {
    {{80.f,104.f},{128.f,240.f},{264.f,184.f}},
    {{480.f,976.f},{992.f,720.f},{944.f,1904.f}},
    {{3712.f,2880.f},{4992.f,6336.f},{11936.f,10432.f}}
};
__constant__ float c_stride[3] = {8.f, 16.f, 32.f};
__constant__ float c_bal[3]    = {4.f, 1.f, 0.4f};
__constant__ int   c_HW[3]     = {6400, 1600, 400};
__constant__ int   c_W[3]      = {80, 40, 20};

__device__ __forceinline__ float bce0(float x) {
    // BCE with target 0: max(x,0) + log(1+exp(-|x|))
    return fmaxf(x, 0.f) + __logf(1.f + __expf(-fabsf(x)));
}

// ---------------------------------------------------------------------------
// Kernel 1 (400 blocks x 256):
//   all blocks      : 252-float4 slice of the dense objectness reduce
//   blocks [0,384)  : positive targets, fully register-resident build
//                     (no LDS, no barrier before the gathers)
//   each block writes ONE float4 partial {box, obj(dense+corr), cls, 0}
// ---------------------------------------------------------------------------
__global__ __launch_bounds__(256) void fused_main(
        const float* __restrict__ p0, const float* __restrict__ p1,
        const float* __restrict__ p2,
        const float* __restrict__ boxes, const int* __restrict__ labels,
        float4* __restrict__ part, float* __restrict__ nposPart)
{
    __shared__ float red[4][4];          // per-wave {dsum, box, objc, cls}

    const int bid  = blockIdx.x;
    const int tid  = threadIdx.x;
    const int lane = tid & 63, wv = tid >> 6;

    const bool isPos = (bid < 384);
    const int s   = bid >> 7;            // valid for pos blocks
    const int b   = (bid >> 3) & 15;
    const int grp = bid & 7;             // target n = grp*4 + wave

    // ---- issue boxes/labels loads first (pos blocks, lanes < 32) ----
    float4 bx; int labl = 0;
    if (isPos && lane < 32) {
        bx   = ((const float4*)boxes)[b * 32 + lane];
        labl = labels[b * 32 + lane];
    }

    // ---------------- dense objectness slice (all blocks) ----------------
    float dsum = 0.f;
    {
        int v = bid * 252 + tid;                 // 400*252 = 100800 exactly
        if (tid < 252) {
            int sc, run, off, HW;
            const float* pred;
            if (v < 76800)      { sc = 0; HW = 6400; run = v / 1600;          off = v - run * 1600;         pred = p0; }
            else if (v < 96000) { sc = 1; HW = 1600; int u = v - 76800; run = u / 400; off = u - run * 400; pred = p1; }
            else                { sc = 2; HW = 400;  int u = v - 96000; run = u / 100; off = u - run * 100; pred = p2; }
            int bb = run / 3, a = run - bb * 3;
            const float4* ptr = (const float4*)(pred + (size_t)(bb * 255 + a * 85 + 4) * HW) + off;
            float4 x = *ptr;
            float w = 0.5f * c_bal[sc];
            dsum = w * (bce0(x.x) + bce0(x.y) + bce0(x.z) + bce0(x.w));
        }
    }

    float boxc = 0.f, objc = 0.f, clsp = 0.f;
    if (isPos) {
        // ---- register target build (lanes < 32 hold target `lane`) ----
        int key = 0; float txl = 0.f, tyl = 0.f, twl = 0.f, thl = 0.f;
        {
            float cx = (bx.x + bx.z) * 0.5f, cy = (bx.y + bx.w) * 0.5f;
            float w  = bx.z - bx.x,          h  = bx.w - bx.y;
            float stride = c_stride[s];
            float xg = cx / stride, yg = cy / stride;
            int W = c_W[s];
            int gi = min(max((int)yg, 0), W - 1);   // row from y
            int gj = min(max((int)xg, 0), W - 1);   // col from x
            int best = 0; float bm = 1e30f;
            for (int k = 0; k < 3; ++k) {
                float aw = c_anch[s][k][0], ah = c_anch[s][k][1];
                float r0 = w / aw, r1 = h / ah;
                float m = fmaxf(r0, 1.f / r0) * fmaxf(r1, 1.f / r1);
                if (m < bm) { bm = m; best = k; }
            }
            float aw = c_anch[s][best][0], ah = c_anch[s][best][1];
            key = (best << 20) | (gi << 10) | gj;
            txl = xg - (float)gj;
            tyl = yg - (float)gi;
            twl = __logf(w / (aw + 1e-16f));
            thl = __logf(h / (ah + 1e-16f));
        }

        // npos: designated wave (block grp==0, wave 0) via shfl-rotate dup test
        if (grp == 0 && wv == 0) {
            bool dup = false;
            for (int d = 1; d < 32; ++d) {
                int nk = __shfl(key, (lane + d) & 31);
                dup |= ((lane + d) < 32) && (nk == key);
            }
            bool winl = (lane < 32) && !dup;
            unsigned long long bal = __ballot(winl);
            if (lane == 0) nposPart[s * 16 + b] = (float)__popcll(bal);
        }

        // this wave's target n: broadcast from lane n, dedup via one ballot
        const int n = grp * 4 + wv;
        int   key_n = __shfl(key, n);
        float tx_n  = __shfl(txl, n);
        float ty_n  = __shfl(tyl, n);
        float tw_n  = __shfl(twl, n);
        float th_n  = __shfl(thl, n);
        int   lab   = __shfl(labl, n);
        unsigned long long dupm =
            __ballot((lane > n) && (lane < 32) && (key == key_n));
        bool win = (dupm == 0ull);        // last-n-wins scatter semantics

        if (win) {
            int a  = key_n >> 20;
            int gi = (key_n >> 10) & 1023;
            int gj = key_n & 1023;
            const int HW = c_HW[s], W = c_W[s];
            int hw = gi * W + gj;
            const float* pred = (s == 0) ? p0 : ((s == 1) ? p1 : p2);
            const float* pb_ = pred + (size_t)(b * 255 + a * 85) * HW + hw;
            const float* pc  = pb_ + (size_t)5 * HW;

            // lane-parallel class logit loads
            float xc0 = pc[(size_t)lane * HW];
            float xc1 = (lane < 16) ? pc[(size_t)(lane + 64) * HW] : 0.f;
            clsp = bce0(xc0) - ((lane == lab) ? xc0 : 0.f);
            if (lane < 16) clsp += bce0(xc1) - ((lane + 64 == lab) ? xc1 : 0.f);

            float px = pb_[0], py = pb_[(size_t)HW];
            float pw = pb_[2 * (size_t)HW], ph = pb_[3 * (size_t)HW];
            float xo = pb_[4 * (size_t)HW];

            // objectness correction:  bal * (0.5*bce0(xo) - xo)
            objc = c_bal[s] * (0.5f * bce0(xo) - xo);

            // CIoU (lane-redundant)
            const float stride = c_stride[s];
            const float aw = c_anch[s][a][0], ah = c_anch[s][a][1];
            float sx = 1.f / (1.f + __expf(-px));
            float sy = 1.f / (1.f + __expf(-py));
            float b1x = (sx + (float)gj) * stride, b1y = (sy + (float)gi) * stride;
            float b1w = __expf(pw) * aw,           b1h = __expf(ph) * ah;
            float b2x = ((float)gj + tx_n) * stride, b2y = ((float)gi + ty_n) * stride;
            float b2w = __expf(tw_n) * aw,           b2h = __expf(th_n) * ah;

            float b1x1 = b1x - b1w * 0.5f, b1x2 = b1x + b1w * 0.5f;
            float b1y1 = b1y - b1h * 0.5f, b1y2 = b1y + b1h * 0.5f;
            float b2x1 = b2x - b2w * 0.5f, b2x2 = b2x + b2w * 0.5f;
            float b2y1 = b2y - b2h * 0.5f, b2y2 = b2y + b2h * 0.5f;
            float iw = fmaxf(fminf(b1x2, b2x2) - fmaxf(b1x1, b2x1), 0.f);
            float ih = fmaxf(fminf(b1y2, b2y2) - fmaxf(b1y1, b2y1), 0.f);
            float inter = iw * ih;
            float uni = b1w * b1h + b2w * b2h - inter + EPSF;
            float iou = inter / uni;
            float cwv = fmaxf(b1x2, b2x2) - fminf(b1x1, b2x1);
            float chv = fmaxf(b1y2, b2y2) - fminf(b1y1, b2y1);
            float c2 = cwv * cwv + chv * chv + EPSF;
            float dx = b2x1 + b2x2 - b1x1 - b1x2;
            float dy = b2y1 + b2y2 - b1y1 - b1y2;
            float rho2 = (dx * dx + dy * dy) * 0.25f;
            float dat = atanf(b2w / (b2h + EPSF)) - atanf(b1w / (b1h + EPSF));
            float v = (4.f / (float)(M_PI * M_PI)) * dat * dat;
            float alpha = v / (v - iou + 1.f + EPSF);
            boxc = 1.f - (iou - (rho2 / c2 + v * alpha));
        }
    }

    // block reduce: {dsum, box, objc, cls} -> one float4 per block
    for (int o = 32; o > 0; o >>= 1) {
        dsum += __shfl_down(dsum, o);
        clsp += __shfl_down(clsp, o);
    }
    if (lane == 0) {
        red[wv][0] = dsum; red[wv][1] = boxc; red[wv][2] = objc; red[wv][3] = clsp;
    }
    __syncthreads();
    if (tid == 0) {
        float d = 0.f, bxs = 0.f, oc = 0.f, cl = 0.f;
        for (int i = 0; i < 4; ++i) {
            d += red[i][0]; bxs += red[i][1]; oc += red[i][2]; cl += red[i][3];
        }
        part[bid] = make_float4(bxs, d + oc, cl, 0.f);   // obj = dense + corr
    }
}

// ---------------------------------------------------------------------------
// Kernel 2: finalize — 400 float4 partials + 48 npos -> out[0]
// ---------------------------------------------------------------------------
__global__ __launch_bounds__(256) void finalize(
        const float4* __restrict__ part, const float* __restrict__ nposPart,
        float* __restrict__ out)
{
    int tid = threadIdx.x;
    float bx0 = 0.f, bx1 = 0.f, bx2 = 0.f, obj = 0.f, cls = 0.f;
    for (int i = tid; i < 400; i += 256) {
        float4 p = part[i];
        obj += p.y;
        cls += p.z;
        int sc = i >> 7;          // 128 blocks per scale; i>=384 -> sc=3 (box=0)
        bx0 += (sc == 0) ? p.x : 0.f;
        bx1 += (sc == 1) ? p.x : 0.f;
        bx2 += (sc == 2) ? p.x : 0.f;
    }
    float np0 = 0.f, np1 = 0.f, np2 = 0.f;
    if (tid < 48) {
        float v = nposPart[tid];
        int sc = tid / 16;
        np0 = (sc == 0) ? v : 0.f;
        np1 = (sc == 1) ? v : 0.f;
        np2 = (sc == 2) ? v : 0.f;
    }

    for (int o = 32; o > 0; o >>= 1) {
        bx0 += __shfl_down(bx0, o);
        bx1 += __shfl_down(bx1, o);
        bx2 += __shfl_down(bx2, o);
        obj += __shfl_down(obj, o);
        cls += __shfl_down(cls, o);
        np0 += __shfl_down(np0, o);
        np1 += __shfl_down(np1, o);
        np2 += __shfl_down(np2, o);
    }
    __shared__ float red[4][8];
    int wv = tid >> 6;
    if ((tid & 63) == 0) {
        red[wv][0] = bx0; red[wv][1] = bx1; red[wv][2] = bx2; red[wv][3] = obj;
        red[wv][4] = cls; red[wv][5] = np0; red[wv][6] = np1; red[wv][7] = np2;
    }
    __syncthreads();
    if (tid == 0) {
        float v[8];
        for (int j = 0; j < 8; ++j)
            v[j] = red[0][j] + red[1][j] + red[2][j] + red[3][j];
        float tot = v[0] / fmaxf(v[5], 1.f)
                  + v[1] / fmaxf(v[6], 1.f)
                  + v[2] / fmaxf(v[7], 1.f)
                  + v[3]               // obj (dense + corrections, bal folded)
                  + 0.5f * v[4];       // LAMBDA_CLS
        out[0] = tot / 16.f;           // / B
    }
}

extern "C" void kernel_launch(void* const* d_in, const int* in_sizes, int n_in,
                              void* d_out, int out_size, void* d_ws, size_t ws_size,
                              hipStream_t stream)
{
    const float* p0     = (const float*)d_in[0];
    const float* p1     = (const float*)d_in[1];
    const float* p2     = (const float*)d_in[2];
    const float* boxes  = (const float*)d_in[3];
    const int*   labels = (const int*)d_in[4];

    char* ws = (char*)d_ws;
    float4* part     = (float4*)ws;             // 400*16 = 6400 B
    float*  nposPart = (float*)(ws + 6656);     // 48*4   = 192 B

    fused_main<<<400, 256, 0, stream>>>(p0, p1, p2, boxes, labels,
                                        part, nposPart);
    finalize<<<1, 256, 0, stream>>>(part, nposPart, (float*)d_out);
}